// Round 2
// baseline (813.368 us; speedup 1.0000x reference)
//
#include <hip/hip_runtime.h>
#include <stdint.h>

typedef unsigned short u16;
typedef __bf16  bf16x8 __attribute__((ext_vector_type(8), may_alias));
typedef u16     u16x8  __attribute__((ext_vector_type(8), may_alias));
typedef float   f32x4  __attribute__((ext_vector_type(4)));
typedef float   f32x4u __attribute__((ext_vector_type(4), may_alias));

#define Bv   2
#define Sv   2048
#define Dv   2048
#define Hv   16
#define KVHv 4
#define HDv  128
#define Tv   (Bv*Sv)      // 4096 tokens
#define QKVN 3072         // 2048 Q + 512 K + 512 V

__device__ __forceinline__ float b2f(u16 u) {
    union { float f; uint32_t i; } x; x.i = ((uint32_t)u) << 16; return x.f;
}
__device__ __forceinline__ u16 f2b(float f) {
    union { float f; uint32_t u; } x; x.f = f;
    uint32_t r = x.u + 0x7fff + ((x.u >> 16) & 1);
    return (u16)(r >> 16);
}
// global -> LDS direct (16B per lane; LDS dest wave-uniform base, HW adds lane*16)
__device__ __forceinline__ void gload_lds16(const void* g, void* l) {
    __builtin_amdgcn_global_load_lds((__attribute__((address_space(1))) void*)(uintptr_t)g,
                                     (__attribute__((address_space(3))) void*)(uintptr_t)l,
                                     16, 0, 0);
}

// ---------- transpose + cast f32->bf16: in (R x C) f32 -> out (C x 4096) bf16 ----------
__global__ void transpose_cast(const float* __restrict__ in, u16* __restrict__ out, int C) {
    __shared__ u16 tile[64][72];
    const int tr = blockIdx.y * 64, tc = blockIdx.x * 64;
    const int tid = threadIdx.x;
#pragma unroll
    for (int i = 0; i < 4; ++i) {
        int s = tid + 256 * i;            // 1024 float4 = 64 rows x 16
        int r = s >> 4, c4 = (s & 15) * 4;
        f32x4u v = *(const f32x4u*)&in[(size_t)(tr + r) * C + tc + c4];
#pragma unroll
        for (int j = 0; j < 4; ++j) tile[r][c4 + j] = f2b(v[j]);
    }
    __syncthreads();
#pragma unroll
    for (int i = 0; i < 2; ++i) {
        int s = tid + 256 * i;
        int r = s >> 3, c8 = (s & 7) * 8;
        u16x8 v;
#pragma unroll
        for (int j = 0; j < 8; ++j) v[j] = tile[c8 + j][r];
        *(u16x8*)&out[(size_t)(tc + r) * 4096 + tr + c8] = v;
    }
}

// ---------- build masked duplicated A (bf16): dst[t][m*Dv+d] = (mod[t]==m) ? src[t][d] : 0 ----------
template <typename T>
__global__ void build_dup(const T* __restrict__ src, const int* __restrict__ mod,
                          u16* __restrict__ dst) {
    int v = blockIdx.x * 256 + threadIdx.x;   // Tv*Dv/8 = 1048576 threads
    int t = v >> 8;                           // Dv/8 = 256 vec8 per row
    int c8 = (v & 255) * 8;
    int m = mod[t];
    u16x8 val;
    if constexpr (sizeof(T) == 4) {           // f32 source -> cast
        f32x4u a = *(const f32x4u*)&src[(size_t)t * Dv + c8];
        f32x4u b = *(const f32x4u*)&src[(size_t)t * Dv + c8 + 4];
#pragma unroll
        for (int j = 0; j < 4; ++j) { val[j] = f2b(a[j]); val[4 + j] = f2b(b[j]); }
    } else {                                  // bf16 source
        val = *(const u16x8*)&src[(size_t)t * Dv + c8];
    }
    u16x8 z = {0, 0, 0, 0, 0, 0, 0, 0};
    u16* base = dst + (size_t)t * (2 * Dv);
    *(u16x8*)&base[m * Dv + c8] = val;
    *(u16x8*)&base[(1 - m) * Dv + c8] = z;
}

// ---------- GEMM: C(MxN) = A(MxK) * Bt(NxK)^T, bf16 in, f32 acc, OutT out ----------
__device__ __forceinline__ void store_c(u16* C, size_t idx, float v) { C[idx] = f2b(v); }
__device__ __forceinline__ void store_c(float* C, size_t idx, float v) { C[idx] = v; }

template <typename OutT>
__global__ __launch_bounds__(256) void gemm_bt(const u16* __restrict__ A,
                                               const u16* __restrict__ Bt,
                                               OutT* __restrict__ C,
                                               int M, int N, int K) {
    __shared__ u16 lA[128 * 64];
    __shared__ u16 lB[128 * 64];
    const int tid = threadIdx.x;
    const int wave = tid >> 6, lane = tid & 63;
    const int l15 = lane & 15, l4 = lane >> 4;
    const int bm = blockIdx.y * 128, bn = blockIdx.x * 128;
    const int wr = (wave >> 1) * 64, wc = (wave & 1) * 64;
    f32x4 acc[4][4] = {};
    for (int kb = 0; kb < K; kb += 64) {
        __syncthreads();
#pragma unroll
        for (int i = 0; i < 4; ++i) {
            int s_u = wave * 64 + 256 * i;
            int s = s_u + lane;
            int r = s >> 3, k8 = (s & 7) * 8;
            gload_lds16(A  + (size_t)(bm + r) * K + kb + k8, &lA[(size_t)s_u * 8]);
            gload_lds16(Bt + (size_t)(bn + r) * K + kb + k8, &lB[(size_t)s_u * 8]);
        }
        __syncthreads();
#pragma unroll
        for (int kc = 0; kc < 2; ++kc) {
            bf16x8 af[4], bfr[4];
#pragma unroll
            for (int i = 0; i < 4; ++i)
                af[i] = *(const bf16x8*)&lA[(wr + i * 16 + l15) * 64 + kc * 32 + l4 * 8];
#pragma unroll
            for (int j = 0; j < 4; ++j)
                bfr[j] = *(const bf16x8*)&lB[(wc + j * 16 + l15) * 64 + kc * 32 + l4 * 8];
#pragma unroll
            for (int i = 0; i < 4; ++i)
#pragma unroll
                for (int j = 0; j < 4; ++j)
                    acc[i][j] = __builtin_amdgcn_mfma_f32_16x16x32_bf16(af[i], bfr[j], acc[i][j], 0, 0, 0);
        }
    }
#pragma unroll
    for (int i = 0; i < 4; ++i)
#pragma unroll
        for (int j = 0; j < 4; ++j) {
            int row = bm + wr + i * 16 + l4 * 4;
            int col = bn + wc + j * 16 + l15;
#pragma unroll
            for (int r = 0; r < 4; ++r)
                store_c(C, (size_t)(row + r) * N + col, acc[i][j][r]);
        }
}

// ---------- RoPE in place on Q,K halves of QKV (bf16); freq_cis f32; folds 1/sqrt(HD) into Q ----------
__global__ void rope_kernel(u16* __restrict__ QKV, const float* __restrict__ fc) {
    int p = blockIdx.x * 256 + threadIdx.x;  // Tv*1280 total pairs
    const int t = p / 1280;
    const int r = p - t * 1280;
    const int s = t & (Sv - 1);
    int col, d2; float scale;
    if (r < 1024) { col = 2 * r;                d2 = r & 63;  scale = 0.08838834764831845f; }
    else          { int rr = r - 1024; col = 2048 + 2 * rr; d2 = rr & 63; scale = 1.0f; }
    u16* ptr = QKV + (size_t)t * QKVN + col;
    float t0 = b2f(ptr[0]), t1 = b2f(ptr[1]);
    f32x4u f = *(const f32x4u*)&fc[((size_t)s * 64 + d2) * 4];   // [c, -s, s, c]
    ptr[0] = f2b((t0 * f[0] + t1 * f[1]) * scale);
    ptr[1] = f2b((t0 * f[2] + t1 * f[3]) * scale);
}

// ---------- causal GQA flash attention; QKV token-major stride 3072; out bf16 token-major 2048 ----------
__global__ __launch_bounds__(256) void attn_fwd(const u16* __restrict__ QKV, u16* __restrict__ O) {
    const int qb = blockIdx.x, h = blockIdx.y, b = blockIdx.z;
    const int kvh = h >> 2;
    const int tid = threadIdx.x, wave = tid >> 6, lane = tid & 63;
    const int l15 = lane & 15, l4 = lane >> 4;
    __shared__ u16 Kl[64 * 128];    // [kv][d]
    __shared__ u16 Vt[128 * 64];    // [d][kv]
    __shared__ u16 Pl[4][16 * 64];  // per-wave P
    bf16x8 qf[4];
    {
        const size_t qrow = (size_t)(b * Sv + qb * 64 + wave * 16 + l15);
#pragma unroll
        for (int kc = 0; kc < 4; ++kc)
            qf[kc] = *(const bf16x8*)&QKV[qrow * QKVN + h * 128 + kc * 32 + l4 * 8];
    }
    f32x4 oacc[8] = {};
    float mrow[4] = {-1e30f, -1e30f, -1e30f, -1e30f};
    float lrow[4] = {0.f, 0.f, 0.f, 0.f};
    for (int j = 0; j <= qb; ++j) {
        __syncthreads();
#pragma unroll
        for (int i = 0; i < 4; ++i) {
            int s_u = wave * 64 + 256 * i;
            int s = s_u + lane;
            int r = s >> 4, c8 = (s & 15) * 8;
            gload_lds16(QKV + (size_t)(b * Sv + j * 64 + r) * QKVN + 2048 + kvh * 128 + c8,
                        &Kl[(size_t)s_u * 8]);
        }
#pragma unroll
        for (int i = 0; i < 4; ++i) {
            int s = wave * 64 + 256 * i + lane;
            int r = s >> 4, c8 = (s & 15) * 8;
            u16x8 v = *(const u16x8*)&QKV[(size_t)(b * Sv + j * 64 + r) * QKVN + 2560 + kvh * 128 + c8];
#pragma unroll
            for (int jj = 0; jj < 8; ++jj) Vt[(c8 + jj) * 64 + r] = v[jj];
        }
        __syncthreads();
        // S = Q K^T  (rows q, cols kv)
        f32x4 sacc[4] = {};
#pragma unroll
        for (int kc = 0; kc < 4; ++kc)
#pragma unroll
            for (int nt = 0; nt < 4; ++nt) {
                bf16x8 kf = *(const bf16x8*)&Kl[(nt * 16 + l15) * 128 + kc * 32 + l4 * 8];
                sacc[nt] = __builtin_amdgcn_mfma_f32_16x16x32_bf16(qf[kc], kf, sacc[nt], 0, 0, 0);
            }
        if (j == qb) {
#pragma unroll
            for (int nt = 0; nt < 4; ++nt)
#pragma unroll
                for (int r = 0; r < 4; ++r)
                    if (64 * j + nt * 16 + l15 > qb * 64 + wave * 16 + l4 * 4 + r)
                        sacc[nt][r] = -1e30f;
        }
        // online softmax per q-row (row r lives in 16-lane group l4, reg r)
#pragma unroll
        for (int r = 0; r < 4; ++r) {
            float mx = fmaxf(fmaxf(sacc[0][r], sacc[1][r]), fmaxf(sacc[2][r], sacc[3][r]));
#pragma unroll
            for (int d = 1; d < 16; d <<= 1) mx = fmaxf(mx, __shfl_xor(mx, d, 64));
            float mnew = fmaxf(mrow[r], mx);
            float fs = __expf(mrow[r] - mnew);
            mrow[r] = mnew;
            float ps = 0.f;
#pragma unroll
            for (int nt = 0; nt < 4; ++nt) {
                float p = __expf(sacc[nt][r] - mnew);
                sacc[nt][r] = p;
                ps += p;
            }
#pragma unroll
            for (int d = 1; d < 16; d <<= 1) ps += __shfl_xor(ps, d, 64);
            lrow[r] = lrow[r] * fs + ps;
#pragma unroll
            for (int nt = 0; nt < 8; ++nt) oacc[nt][r] *= fs;
        }
        // P -> LDS (bf16), read back as PV A-fragments (per-wave area; same-wave RAW)
#pragma unroll
        for (int nt = 0; nt < 4; ++nt)
#pragma unroll
            for (int r = 0; r < 4; ++r)
                Pl[wave][(l4 * 4 + r) * 64 + nt * 16 + l15] = f2b(sacc[nt][r]);
        bf16x8 pf0 = *(const bf16x8*)&Pl[wave][l15 * 64 + l4 * 8];
        bf16x8 pf1 = *(const bf16x8*)&Pl[wave][l15 * 64 + 32 + l4 * 8];
#pragma unroll
        for (int nt = 0; nt < 8; ++nt) {
            bf16x8 v0 = *(const bf16x8*)&Vt[(nt * 16 + l15) * 64 + l4 * 8];
            bf16x8 v1 = *(const bf16x8*)&Vt[(nt * 16 + l15) * 64 + 32 + l4 * 8];
            oacc[nt] = __builtin_amdgcn_mfma_f32_16x16x32_bf16(pf0, v0, oacc[nt], 0, 0, 0);
            oacc[nt] = __builtin_amdgcn_mfma_f32_16x16x32_bf16(pf1, v1, oacc[nt], 0, 0, 0);
        }
    }
#pragma unroll
    for (int nt = 0; nt < 8; ++nt)
#pragma unroll
        for (int r = 0; r < 4; ++r) {
            int qg = qb * 64 + wave * 16 + l4 * 4 + r;
            O[(size_t)(b * Sv + qg) * 2048 + h * 128 + nt * 16 + l15] = f2b(oacc[nt][r] / lrow[r]);
        }
}

extern "C" void kernel_launch(void* const* d_in, const int* in_sizes, int n_in,
                              void* d_out, int out_size, void* d_ws, size_t ws_size,
                              hipStream_t stream) {
    const float* x   = (const float*)d_in[0];
    const float* fc  = (const float*)d_in[1];
    const int*   mod = (const int*)d_in[2];
    const float* wq  = (const float*)d_in[3];
    const float* wk  = (const float*)d_in[4];
    const float* wv  = (const float*)d_in[5];
    const float* wo  = (const float*)d_in[6];
    float* out = (float*)d_out;
    char* ws = (char*)d_ws;
    // workspace layout (bytes): total 100,663,296
    u16* Wqkv_t = (u16*)(ws);               // 3072 x 4096 bf16 (25.2 MB)
    u16* Wo_t   = (u16*)(ws + 25165824);    // 2048 x 4096 bf16 (16.8 MB)
    u16* Xdup   = (u16*)(ws + 41943040);    // 4096 x 4096 bf16 (33.6 MB), reused for Adup
    u16* QKV    = (u16*)(ws + 75497472);    // 4096 x 3072 bf16 (25.2 MB)
    u16* Attn   = (u16*)(ws);               // 4096 x 2048 bf16, aliases dead Wqkv_t region

    // weights -> B^T (N x K=4096) bf16
    transpose_cast<<<dim3(32, 64), 256, 0, stream>>>(wq, Wqkv_t, 2048);
    transpose_cast<<<dim3(8, 64),  256, 0, stream>>>(wk, Wqkv_t + (size_t)2048 * 4096, 512);
    transpose_cast<<<dim3(8, 64),  256, 0, stream>>>(wv, Wqkv_t + (size_t)2560 * 4096, 512);
    transpose_cast<<<dim3(32, 64), 256, 0, stream>>>(wo, Wo_t, 2048);
    // masked duplicated activations (f32 x -> bf16 Xdup)
    build_dup<float><<<4096, 256, 0, stream>>>(x, mod, Xdup);
    // QKV = Xdup (4096x4096) @ Wqkv' (4096x3072), bf16 out
    gemm_bt<u16><<<dim3(24, 32), 256, 0, stream>>>(Xdup, Wqkv_t, QKV, 4096, 3072, 4096);
    // RoPE on Q,K (+ fold score scale into Q)
    rope_kernel<<<20480, 256, 0, stream>>>(QKV, fc);
    // causal GQA attention -> Attn bf16
    attn_fwd<<<dim3(32, 16, 2), 256, 0, stream>>>(QKV, Attn);
    // output projection -> f32 out
    build_dup<u16><<<4096, 256, 0, stream>>>(Attn, mod, Xdup);
    gemm_bt<float><<<dim3(16, 32), 256, 0, stream>>>(Xdup, Wo_t, out, 4096, 2048, 4096);
}

// Round 3
// 696.767 us; speedup vs baseline: 1.1673x; 1.1673x over previous
//
#include <hip/hip_runtime.h>
#include <stdint.h>

typedef unsigned short u16;
typedef __bf16  bf16x8 __attribute__((ext_vector_type(8), may_alias));
typedef u16     u16x8  __attribute__((ext_vector_type(8), may_alias));
typedef float   f32x4  __attribute__((ext_vector_type(4)));
typedef float   f32x4u __attribute__((ext_vector_type(4), may_alias));

#define Bv   2
#define Sv   2048
#define Dv   2048
#define Hv   16
#define KVHv 4
#define HDv  128
#define Tv   (Bv*Sv)      // 4096 tokens
#define QKVN 3072         // 2048 Q + 512 K + 512 V

__device__ __forceinline__ float b2f(u16 u) {
    union { float f; uint32_t i; } x; x.i = ((uint32_t)u) << 16; return x.f;
}
__device__ __forceinline__ u16 f2b(float f) {
    union { float f; uint32_t u; } x; x.f = f;
    uint32_t r = x.u + 0x7fff + ((x.u >> 16) & 1);
    return (u16)(r >> 16);
}
// global -> LDS direct (16B per lane; LDS dest wave-uniform base, HW adds lane*16)
__device__ __forceinline__ void gload_lds16(const void* g, void* l) {
    __builtin_amdgcn_global_load_lds((__attribute__((address_space(1))) void*)(uintptr_t)g,
                                     (__attribute__((address_space(3))) void*)(uintptr_t)l,
                                     16, 0, 0);
}

// ---------- transpose + cast f32->bf16: in (R x C) f32 -> out (C x 4096) bf16 ----------
__global__ void transpose_cast(const float* __restrict__ in, u16* __restrict__ out, int C) {
    __shared__ u16 tile[64][72];
    const int tr = blockIdx.y * 64, tc = blockIdx.x * 64;
    const int tid = threadIdx.x;
#pragma unroll
    for (int i = 0; i < 4; ++i) {
        int s = tid + 256 * i;            // 1024 float4 = 64 rows x 16
        int r = s >> 4, c4 = (s & 15) * 4;
        f32x4u v = *(const f32x4u*)&in[(size_t)(tr + r) * C + tc + c4];
#pragma unroll
        for (int j = 0; j < 4; ++j) tile[r][c4 + j] = f2b(v[j]);
    }
    __syncthreads();
#pragma unroll
    for (int i = 0; i < 2; ++i) {
        int s = tid + 256 * i;
        int r = s >> 3, c8 = (s & 7) * 8;
        u16x8 v;
#pragma unroll
        for (int j = 0; j < 8; ++j) v[j] = tile[c8 + j][r];
        *(u16x8*)&out[(size_t)(tc + r) * 4096 + tr + c8] = v;
    }
}

// ---------- build masked duplicated A (bf16): dst[t][m*Dv+d] = (mod[t]==m) ? src[t][d] : 0 ----------
template <typename T>
__global__ void build_dup(const T* __restrict__ src, const int* __restrict__ mod,
                          u16* __restrict__ dst) {
    int v = blockIdx.x * 256 + threadIdx.x;   // Tv*Dv/8 = 1048576 threads
    int t = v >> 8;                           // Dv/8 = 256 vec8 per row
    int c8 = (v & 255) * 8;
    int m = mod[t];
    u16x8 val;
    if constexpr (sizeof(T) == 4) {           // f32 source -> cast
        f32x4u a = *(const f32x4u*)&src[(size_t)t * Dv + c8];
        f32x4u b = *(const f32x4u*)&src[(size_t)t * Dv + c8 + 4];
#pragma unroll
        for (int j = 0; j < 4; ++j) { val[j] = f2b(a[j]); val[4 + j] = f2b(b[j]); }
    } else {                                  // bf16 source
        val = *(const u16x8*)&src[(size_t)t * Dv + c8];
    }
    u16x8 z = {0, 0, 0, 0, 0, 0, 0, 0};
    u16* base = dst + (size_t)t * (2 * Dv);
    *(u16x8*)&base[m * Dv + c8] = val;
    *(u16x8*)&base[(1 - m) * Dv + c8] = z;
}

// ---------- GEMM: C(MxN) = A(MxK) * Bt(NxK)^T, bf16 in, f32 acc, OutT out ----------
__device__ __forceinline__ void store_c(u16* C, size_t idx, float v) { C[idx] = f2b(v); }
__device__ __forceinline__ void store_c(float* C, size_t idx, float v) { C[idx] = v; }

template <typename OutT>
__global__ __launch_bounds__(256) void gemm_bt(const u16* __restrict__ A,
                                               const u16* __restrict__ Bt,
                                               OutT* __restrict__ C,
                                               int M, int N, int K) {
    __shared__ u16 lA[128 * 64];
    __shared__ u16 lB[128 * 64];
    const int tid = threadIdx.x;
    const int wave = tid >> 6, lane = tid & 63;
    const int l15 = lane & 15, l4 = lane >> 4;
    const int bm = blockIdx.y * 128, bn = blockIdx.x * 128;
    const int wr = (wave >> 1) * 64, wc = (wave & 1) * 64;
    f32x4 acc[4][4] = {};
    for (int kb = 0; kb < K; kb += 64) {
        __syncthreads();
#pragma unroll
        for (int i = 0; i < 4; ++i) {
            int s_u = wave * 64 + 256 * i;
            int s = s_u + lane;
            int r = s >> 3, k8 = (s & 7) * 8;
            gload_lds16(A  + (size_t)(bm + r) * K + kb + k8, &lA[(size_t)s_u * 8]);
            gload_lds16(Bt + (size_t)(bn + r) * K + kb + k8, &lB[(size_t)s_u * 8]);
        }
        __syncthreads();
#pragma unroll
        for (int kc = 0; kc < 2; ++kc) {
            bf16x8 af[4], bfr[4];
#pragma unroll
            for (int i = 0; i < 4; ++i)
                af[i] = *(const bf16x8*)&lA[(wr + i * 16 + l15) * 64 + kc * 32 + l4 * 8];
#pragma unroll
            for (int j = 0; j < 4; ++j)
                bfr[j] = *(const bf16x8*)&lB[(wc + j * 16 + l15) * 64 + kc * 32 + l4 * 8];
#pragma unroll
            for (int i = 0; i < 4; ++i)
#pragma unroll
                for (int j = 0; j < 4; ++j)
                    acc[i][j] = __builtin_amdgcn_mfma_f32_16x16x32_bf16(af[i], bfr[j], acc[i][j], 0, 0, 0);
        }
    }
#pragma unroll
    for (int i = 0; i < 4; ++i)
#pragma unroll
        for (int j = 0; j < 4; ++j) {
            int row = bm + wr + i * 16 + l4 * 4;
            int col = bn + wc + j * 16 + l15;
#pragma unroll
            for (int r = 0; r < 4; ++r)
                store_c(C, (size_t)(row + r) * N + col, acc[i][j][r]);
        }
}

// ---------- RoPE in place on Q,K halves of QKV (bf16); freq_cis f32; folds 1/sqrt(HD) into Q ----------
__global__ void rope_kernel(u16* __restrict__ QKV, const float* __restrict__ fc) {
    int p = blockIdx.x * 256 + threadIdx.x;  // Tv*1280 total pairs
    const int t = p / 1280;
    const int r = p - t * 1280;
    const int s = t & (Sv - 1);
    int col, d2; float scale;
    if (r < 1024) { col = 2 * r;                d2 = r & 63;  scale = 0.08838834764831845f; }
    else          { int rr = r - 1024; col = 2048 + 2 * rr; d2 = rr & 63; scale = 1.0f; }
    u16* ptr = QKV + (size_t)t * QKVN + col;
    float t0 = b2f(ptr[0]), t1 = b2f(ptr[1]);
    f32x4u f = *(const f32x4u*)&fc[((size_t)s * 64 + d2) * 4];   // [c, -s, s, c]
    ptr[0] = f2b((t0 * f[0] + t1 * f[1]) * scale);
    ptr[1] = f2b((t0 * f[2] + t1 * f[3]) * scale);
}

// ---------- causal GQA flash attention; QKV token-major stride 3072; out bf16 token-major 2048 ----------
// LDS layouts (all XOR-swizzled, both-sides involution):
//   Kl: [kv 0..63][128 d], row 256B = 16 slots x 16B; data col-slot c stored at c ^ (kv&7)
//   Vt: [d 0..127][64 kv], row 128B = 8 slots x 8 kv;  kv-slot (kv>>3) stored at (kv>>3)^(d&7)
//   Pl: [q 0..15][64 k],   row 128B = 8 slots;          k-slot  (k>>3) stored at (k>>3)^(q&7)
__global__ __launch_bounds__(256) void attn_fwd(const u16* __restrict__ QKV, u16* __restrict__ O) {
    // balanced q-tile mapping: consecutive blocks pair (qb, 31-qb) so per-CU work is even
    const int qi = blockIdx.x;
    const int qb = (qi & 1) ? (31 - (qi >> 1)) : (qi >> 1);
    const int h = blockIdx.y, b = blockIdx.z;
    const int kvh = h >> 2;
    const int tid = threadIdx.x, wave = tid >> 6, lane = tid & 63;
    const int l15 = lane & 15, l4 = lane >> 4;
    __shared__ u16 Kl[64 * 128];
    __shared__ u16 Vt[128 * 64];
    __shared__ u16 Pl[4][16 * 64];
    bf16x8 qf[4];
    {
        const size_t qrow = (size_t)(b * Sv + qb * 64 + wave * 16 + l15);
#pragma unroll
        for (int kc = 0; kc < 4; ++kc)
            qf[kc] = *(const bf16x8*)&QKV[qrow * QKVN + h * 128 + kc * 32 + l4 * 8];
    }
    f32x4 oacc[8] = {};
    float mrow[4] = {-1e30f, -1e30f, -1e30f, -1e30f};
    float lrow[4] = {0.f, 0.f, 0.f, 0.f};
    for (int j = 0; j <= qb; ++j) {
        __syncthreads();
        // K stage: linear LDS dest, pre-swizzled global col-slot (rule #21)
#pragma unroll
        for (int i = 0; i < 4; ++i) {
            int s_u = wave * 64 + 256 * i;
            int s = s_u + lane;
            int r = s >> 4;                      // kv row
            int cs = (s & 15) ^ (r & 7);         // global 16B col-slot
            gload_lds16(QKV + (size_t)(b * Sv + j * 64 + r) * QKVN + 2048 + kvh * 128 + cs * 8,
                        &Kl[(size_t)s_u * 8]);
        }
        // V stage: kv = lane (writes sweep rows), swizzled scalar writes (2-way free)
#pragma unroll
        for (int i = 0; i < 4; ++i) {
            int db = i * 4 + wave;               // d-block 0..15
            u16x8 v = *(const u16x8*)&QKV[(size_t)(b * Sv + j * 64 + lane) * QKVN + 2560 + kvh * 128 + db * 8];
#pragma unroll
            for (int jj = 0; jj < 8; ++jj) {
                int d = db * 8 + jj;             // d&7 == jj
                Vt[d * 64 + ((((lane >> 3) ^ jj) << 3) | (lane & 7))] = v[jj];
            }
        }
        __syncthreads();
        // S = Q K^T  (rows q, cols kv)
        f32x4 sacc[4] = {};
#pragma unroll
        for (int kc = 0; kc < 4; ++kc)
#pragma unroll
            for (int nt = 0; nt < 4; ++nt) {
                int cs = ((kc * 4 + l4) ^ (l15 & 7));   // ^ (row&7), row = nt*16+l15
                bf16x8 kf = *(const bf16x8*)&Kl[(nt * 16 + l15) * 128 + cs * 8];
                sacc[nt] = __builtin_amdgcn_mfma_f32_16x16x32_bf16(qf[kc], kf, sacc[nt], 0, 0, 0);
            }
        if (j == qb) {
#pragma unroll
            for (int nt = 0; nt < 4; ++nt)
#pragma unroll
                for (int r = 0; r < 4; ++r)
                    if (64 * j + nt * 16 + l15 > qb * 64 + wave * 16 + l4 * 4 + r)
                        sacc[nt][r] = -1e30f;
        }
        // online softmax per q-row (row r lives in 16-lane group l4, reg r)
#pragma unroll
        for (int r = 0; r < 4; ++r) {
            float mx = fmaxf(fmaxf(sacc[0][r], sacc[1][r]), fmaxf(sacc[2][r], sacc[3][r]));
#pragma unroll
            for (int d = 1; d < 16; d <<= 1) mx = fmaxf(mx, __shfl_xor(mx, d, 64));
            float mnew = fmaxf(mrow[r], mx);
            float fs = __expf(mrow[r] - mnew);
            mrow[r] = mnew;
            float ps = 0.f;
#pragma unroll
            for (int nt = 0; nt < 4; ++nt) {
                float p = __expf(sacc[nt][r] - mnew);
                sacc[nt][r] = p;
                ps += p;
            }
#pragma unroll
            for (int d = 1; d < 16; d <<= 1) ps += __shfl_xor(ps, d, 64);
            lrow[r] = lrow[r] * fs + ps;
#pragma unroll
            for (int nt = 0; nt < 8; ++nt) oacc[nt][r] *= fs;
        }
        // P -> LDS (bf16, swizzled), read back as PV A-fragments (per-wave area)
#pragma unroll
        for (int nt = 0; nt < 4; ++nt)
#pragma unroll
            for (int r = 0; r < 4; ++r) {
                int qrow = l4 * 4 + r;
                int k = nt * 16 + l15;
                Pl[wave][qrow * 64 + ((((k >> 3) ^ (qrow & 7)) << 3) | (k & 7))] = f2b(sacc[nt][r]);
            }
        bf16x8 pf0 = *(const bf16x8*)&Pl[wave][l15 * 64 + ((l4 ^ (l15 & 7)) << 3)];
        bf16x8 pf1 = *(const bf16x8*)&Pl[wave][l15 * 64 + (((4 + l4) ^ (l15 & 7)) << 3)];
#pragma unroll
        for (int nt = 0; nt < 8; ++nt) {
            int d = nt * 16 + l15;               // d&7 == l15&7
            bf16x8 v0 = *(const bf16x8*)&Vt[d * 64 + ((l4 ^ (l15 & 7)) << 3)];
            bf16x8 v1 = *(const bf16x8*)&Vt[d * 64 + (((4 + l4) ^ (l15 & 7)) << 3)];
            oacc[nt] = __builtin_amdgcn_mfma_f32_16x16x32_bf16(pf0, v0, oacc[nt], 0, 0, 0);
            oacc[nt] = __builtin_amdgcn_mfma_f32_16x16x32_bf16(pf1, v1, oacc[nt], 0, 0, 0);
        }
    }
#pragma unroll
    for (int nt = 0; nt < 8; ++nt)
#pragma unroll
        for (int r = 0; r < 4; ++r) {
            int qg = qb * 64 + wave * 16 + l4 * 4 + r;
            O[(size_t)(b * Sv + qg) * 2048 + h * 128 + nt * 16 + l15] = f2b(oacc[nt][r] / lrow[r]);
        }
}

extern "C" void kernel_launch(void* const* d_in, const int* in_sizes, int n_in,
                              void* d_out, int out_size, void* d_ws, size_t ws_size,
                              hipStream_t stream) {
    const float* x   = (const float*)d_in[0];
    const float* fc  = (const float*)d_in[1];
    const int*   mod = (const int*)d_in[2];
    const float* wq  = (const float*)d_in[3];
    const float* wk  = (const float*)d_in[4];
    const float* wv  = (const float*)d_in[5];
    const float* wo  = (const float*)d_in[6];
    float* out = (float*)d_out;
    char* ws = (char*)d_ws;
    // workspace layout (bytes): total 100,663,296
    u16* Wqkv_t = (u16*)(ws);               // 3072 x 4096 bf16 (25.2 MB)
    u16* Wo_t   = (u16*)(ws + 25165824);    // 2048 x 4096 bf16 (16.8 MB)
    u16* Xdup   = (u16*)(ws + 41943040);    // 4096 x 4096 bf16 (33.6 MB), reused for Adup
    u16* QKV    = (u16*)(ws + 75497472);    // 4096 x 3072 bf16 (25.2 MB)
    u16* Attn   = (u16*)(ws);               // 4096 x 2048 bf16, aliases dead Wqkv_t region

    // weights -> B^T (N x K=4096) bf16
    transpose_cast<<<dim3(32, 64), 256, 0, stream>>>(wq, Wqkv_t, 2048);
    transpose_cast<<<dim3(8, 64),  256, 0, stream>>>(wk, Wqkv_t + (size_t)2048 * 4096, 512);
    transpose_cast<<<dim3(8, 64),  256, 0, stream>>>(wv, Wqkv_t + (size_t)2560 * 4096, 512);
    transpose_cast<<<dim3(32, 64), 256, 0, stream>>>(wo, Wo_t, 2048);
    // masked duplicated activations (f32 x -> bf16 Xdup)
    build_dup<float><<<4096, 256, 0, stream>>>(x, mod, Xdup);
    // QKV = Xdup (4096x4096) @ Wqkv' (4096x3072), bf16 out
    gemm_bt<u16><<<dim3(24, 32), 256, 0, stream>>>(Xdup, Wqkv_t, QKV, 4096, 3072, 4096);
    // RoPE on Q,K (+ fold score scale into Q)
    rope_kernel<<<20480, 256, 0, stream>>>(QKV, fc);
    // causal GQA attention -> Attn bf16
    attn_fwd<<<dim3(32, 16, 2), 256, 0, stream>>>(QKV, Attn);
    // output projection -> f32 out
    build_dup<u16><<<4096, 256, 0, stream>>>(Attn, mod, Xdup);
    gemm_bt<float><<<dim3(16, 32), 256, 0, stream>>>(Xdup, Wo_t, out, 4096, 2048, 4096);
}

// Round 4
// 461.074 us; speedup vs baseline: 1.7641x; 1.5112x over previous
//
#include <hip/hip_runtime.h>
#include <stdint.h>

typedef unsigned short u16;
typedef __bf16  bf16x8 __attribute__((ext_vector_type(8), may_alias));
typedef u16     u16x8  __attribute__((ext_vector_type(8), may_alias));
typedef float   f32x4  __attribute__((ext_vector_type(4)));
typedef float   f32x4u __attribute__((ext_vector_type(4), may_alias));

#define Bv   2
#define Sv   2048
#define Dv   2048
#define Hv   16
#define KVHv 4
#define HDv  128
#define Tv   (Bv*Sv)      // 4096 tokens
#define QKVN 3072         // 2048 Q + 512 K + 512 V

__device__ __forceinline__ float b2f(u16 u) {
    union { float f; uint32_t i; } x; x.i = ((uint32_t)u) << 16; return x.f;
}
__device__ __forceinline__ u16 f2b(float f) {
    union { float f; uint32_t u; } x; x.f = f;
    uint32_t r = x.u + 0x7fff + ((x.u >> 16) & 1);
    return (u16)(r >> 16);
}
// global -> LDS direct (16B per lane; LDS dest wave-uniform base, HW adds lane*16)
__device__ __forceinline__ void gload_lds16(const void* g, void* l) {
    __builtin_amdgcn_global_load_lds((__attribute__((address_space(1))) void*)(uintptr_t)g,
                                     (__attribute__((address_space(3))) void*)(uintptr_t)l,
                                     16, 0, 0);
}

// ---------- transpose + cast f32->bf16: in (R x C) f32 -> out (C x 4096) bf16 ----------
__global__ void transpose_cast(const float* __restrict__ in, u16* __restrict__ out, int C) {
    __shared__ u16 tile[64][72];
    const int tr = blockIdx.y * 64, tc = blockIdx.x * 64;
    const int tid = threadIdx.x;
#pragma unroll
    for (int i = 0; i < 4; ++i) {
        int s = tid + 256 * i;            // 1024 float4 = 64 rows x 16
        int r = s >> 4, c4 = (s & 15) * 4;
        f32x4u v = *(const f32x4u*)&in[(size_t)(tr + r) * C + tc + c4];
#pragma unroll
        for (int j = 0; j < 4; ++j) tile[r][c4 + j] = f2b(v[j]);
    }
    __syncthreads();
#pragma unroll
    for (int i = 0; i < 2; ++i) {
        int s = tid + 256 * i;
        int r = s >> 3, c8 = (s & 7) * 8;
        u16x8 v;
#pragma unroll
        for (int j = 0; j < 8; ++j) v[j] = tile[c8 + j][r];
        *(u16x8*)&out[(size_t)(tc + r) * 4096 + tr + c8] = v;
    }
}

// ---------- build masked duplicated A (bf16): dst[t][m*Dv+d] = (mod[t]==m) ? src[t][d] : 0 ----------
template <typename T>
__global__ void build_dup(const T* __restrict__ src, const int* __restrict__ mod,
                          u16* __restrict__ dst) {
    int v = blockIdx.x * 256 + threadIdx.x;   // Tv*Dv/8 = 1048576 threads
    int t = v >> 8;                           // Dv/8 = 256 vec8 per row
    int c8 = (v & 255) * 8;
    int m = mod[t];
    u16x8 val;
    if constexpr (sizeof(T) == 4) {           // f32 source -> cast
        f32x4u a = *(const f32x4u*)&src[(size_t)t * Dv + c8];
        f32x4u b = *(const f32x4u*)&src[(size_t)t * Dv + c8 + 4];
#pragma unroll
        for (int j = 0; j < 4; ++j) { val[j] = f2b(a[j]); val[4 + j] = f2b(b[j]); }
    } else {                                  // bf16 source
        val = *(const u16x8*)&src[(size_t)t * Dv + c8];
    }
    u16x8 z = {0, 0, 0, 0, 0, 0, 0, 0};
    u16* base = dst + (size_t)t * (2 * Dv);
    *(u16x8*)&base[m * Dv + c8] = val;
    *(u16x8*)&base[(1 - m) * Dv + c8] = z;
}

// ---------- GEMM: C(MxN) = A(MxK) * Bt(NxK)^T, bf16 in, f32 acc, OutT out ----------
__device__ __forceinline__ void store_c(u16* C, size_t idx, float v) { C[idx] = f2b(v); }
__device__ __forceinline__ void store_c(float* C, size_t idx, float v) { C[idx] = v; }

template <typename OutT>
__global__ __launch_bounds__(256) void gemm_bt(const u16* __restrict__ A,
                                               const u16* __restrict__ Bt,
                                               OutT* __restrict__ C,
                                               int M, int N, int K) {
    __shared__ u16 lA[128 * 64];
    __shared__ u16 lB[128 * 64];
    const int tid = threadIdx.x;
    const int wave = tid >> 6, lane = tid & 63;
    const int l15 = lane & 15, l4 = lane >> 4;
    const int bm = blockIdx.y * 128, bn = blockIdx.x * 128;
    const int wr = (wave >> 1) * 64, wc = (wave & 1) * 64;
    f32x4 acc[4][4] = {};
    for (int kb = 0; kb < K; kb += 64) {
        __syncthreads();
#pragma unroll
        for (int i = 0; i < 4; ++i) {
            int s_u = wave * 64 + 256 * i;
            int s = s_u + lane;
            int r = s >> 3, k8 = (s & 7) * 8;
            gload_lds16(A  + (size_t)(bm + r) * K + kb + k8, &lA[(size_t)s_u * 8]);
            gload_lds16(Bt + (size_t)(bn + r) * K + kb + k8, &lB[(size_t)s_u * 8]);
        }
        __syncthreads();
#pragma unroll
        for (int kc = 0; kc < 2; ++kc) {
            bf16x8 af[4], bfr[4];
#pragma unroll
            for (int i = 0; i < 4; ++i)
                af[i] = *(const bf16x8*)&lA[(wr + i * 16 + l15) * 64 + kc * 32 + l4 * 8];
#pragma unroll
            for (int j = 0; j < 4; ++j)
                bfr[j] = *(const bf16x8*)&lB[(wc + j * 16 + l15) * 64 + kc * 32 + l4 * 8];
#pragma unroll
            for (int i = 0; i < 4; ++i)
#pragma unroll
                for (int j = 0; j < 4; ++j)
                    acc[i][j] = __builtin_amdgcn_mfma_f32_16x16x32_bf16(af[i], bfr[j], acc[i][j], 0, 0, 0);
        }
    }
#pragma unroll
    for (int i = 0; i < 4; ++i)
#pragma unroll
        for (int j = 0; j < 4; ++j) {
            int row = bm + wr + i * 16 + l4 * 4;
            int col = bn + wc + j * 16 + l15;
#pragma unroll
            for (int r = 0; r < 4; ++r)
                store_c(C, (size_t)(row + r) * N + col, acc[i][j][r]);
        }
}

// ---------- RoPE in place on Q,K halves of QKV (bf16); freq_cis f32; folds 1/sqrt(HD) into Q ----------
__global__ void rope_kernel(u16* __restrict__ QKV, const float* __restrict__ fc) {
    int p = blockIdx.x * 256 + threadIdx.x;  // Tv*1280 total pairs
    const int t = p / 1280;
    const int r = p - t * 1280;
    const int s = t & (Sv - 1);
    int col, d2; float scale;
    if (r < 1024) { col = 2 * r;                d2 = r & 63;  scale = 0.08838834764831845f; }
    else          { int rr = r - 1024; col = 2048 + 2 * rr; d2 = rr & 63; scale = 1.0f; }
    u16* ptr = QKV + (size_t)t * QKVN + col;
    float t0 = b2f(ptr[0]), t1 = b2f(ptr[1]);
    f32x4u f = *(const f32x4u*)&fc[((size_t)s * 64 + d2) * 4];   // [c, -s, s, c]
    ptr[0] = f2b((t0 * f[0] + t1 * f[1]) * scale);
    ptr[1] = f2b((t0 * f[2] + t1 * f[3]) * scale);
}

// ---------- causal GQA flash attention ----------
// 512 threads = 8 waves; wave-group 0 (waves 0-3) owns q-tile p, group 1 (waves 4-7) owns 31-p.
// Both groups share K/V staging (same kvh). Every block: 32 staged tiles + 33 compute-tiles
// total -> uniform work, scheduler-independent balance.
// 2-phase pipeline: double-buffered K (global_load_lds) + V (reg-stage, issue-early/write-late).
// LDS swizzles (both-sides involution):
//   Kb: [kv][128 d], 16B col-slot c stored at c ^ (kv&7)
//   Vb: [d][64 kv], 8-kv slot s stored at s ^ (d&7)
//   Pl: [q][64 k],  8-k  slot s stored at s ^ (q&7)
__global__ __launch_bounds__(512) void attn_fwd(const u16* __restrict__ QKV, u16* __restrict__ O) {
    const int p = blockIdx.x;                 // pair id 0..15
    const int h = blockIdx.y, b = blockIdx.z;
    const int kvh = h >> 2;
    const int tid = threadIdx.x, wave = tid >> 6, lane = tid & 63;
    const int wgrp = wave >> 2, wl = wave & 3;
    const int l15 = lane & 15, l4 = lane >> 4;
    const int myqb = wgrp ? (31 - p) : p;     // this wave-group's q-tile
    __shared__ u16 Kb[2][64 * 128];
    __shared__ u16 Vb[2][128 * 64];
    __shared__ u16 Pl[8][16 * 64];

    bf16x8 qf[4];
    {
        const size_t qrow = (size_t)(b * Sv + myqb * 64 + wl * 16 + l15);
#pragma unroll
        for (int kc = 0; kc < 4; ++kc)
            qf[kc] = *(const bf16x8*)&QKV[qrow * QKVN + h * 128 + kc * 32 + l4 * 8];
    }
    f32x4 oacc[8] = {};
    float mrow[4] = {-1e30f, -1e30f, -1e30f, -1e30f};
    float lrow[4] = {0.f, 0.f, 0.f, 0.f};

    const size_t kvbase = (size_t)b * Sv * QKVN + 2048 + kvh * 128;

    // ---- prologue: stage tile 0 into buffer 0 ----
    {
#pragma unroll
        for (int i = 0; i < 2; ++i) {
            int s_u = wave * 64 + 512 * i;
            int s = s_u + lane;
            int r = s >> 4;
            int cs = (s & 15) ^ (r & 7);
            gload_lds16(QKV + kvbase + (size_t)r * QKVN + cs * 8, &Kb[0][(size_t)s_u * 8]);
        }
        u16x8 vr0, vr1;
        vr0 = *(const u16x8*)&QKV[kvbase + 512 + (size_t)lane * QKVN + (0 * 8 + wave) * 8];
        vr1 = *(const u16x8*)&QKV[kvbase + 512 + (size_t)lane * QKVN + (1 * 8 + wave) * 8];
#pragma unroll
        for (int jj = 0; jj < 8; ++jj) {
            int d0 = wave * 8 + jj, d1 = (8 + wave) * 8 + jj;
            Vb[0][d0 * 64 + ((((lane >> 3) ^ jj) << 3) | (lane & 7))] = vr0[jj];
            Vb[0][d1 * 64 + ((((lane >> 3) ^ jj) << 3) | (lane & 7))] = vr1[jj];
        }
    }
    __syncthreads();

    for (int j = 0; j < 32; ++j) {
        const int cur = j & 1;
        const bool stage_next = (j < 31);
        u16x8 vn0, vn1;
        // ---- issue next tile's loads (async; hides under compute) ----
        if (stage_next) {
            const size_t nb = kvbase + (size_t)(j + 1) * 64 * QKVN;
#pragma unroll
            for (int i = 0; i < 2; ++i) {
                int s_u = wave * 64 + 512 * i;
                int s = s_u + lane;
                int r = s >> 4;
                int cs = (s & 15) ^ (r & 7);
                gload_lds16(QKV + nb + (size_t)r * QKVN + cs * 8, &Kb[cur ^ 1][(size_t)s_u * 8]);
            }
            vn0 = *(const u16x8*)&QKV[nb + 512 + (size_t)lane * QKVN + (0 * 8 + wave) * 8];
            vn1 = *(const u16x8*)&QKV[nb + 512 + (size_t)lane * QKVN + (1 * 8 + wave) * 8];
        }
        // ---- compute on current buffer (only if this group's q-tile needs tile j) ----
        if (j <= myqb) {
            f32x4 sacc[4] = {};
#pragma unroll
            for (int kc = 0; kc < 4; ++kc)
#pragma unroll
                for (int nt = 0; nt < 4; ++nt) {
                    int cs = ((kc * 4 + l4) ^ (l15 & 7));
                    bf16x8 kf = *(const bf16x8*)&Kb[cur][(nt * 16 + l15) * 128 + cs * 8];
                    sacc[nt] = __builtin_amdgcn_mfma_f32_16x16x32_bf16(qf[kc], kf, sacc[nt], 0, 0, 0);
                }
            if (j == myqb) {
#pragma unroll
                for (int nt = 0; nt < 4; ++nt)
#pragma unroll
                    for (int r = 0; r < 4; ++r)
                        if (nt * 16 + l15 > wl * 16 + l4 * 4 + r)
                            sacc[nt][r] = -1e30f;
            }
#pragma unroll
            for (int r = 0; r < 4; ++r) {
                float mx = fmaxf(fmaxf(sacc[0][r], sacc[1][r]), fmaxf(sacc[2][r], sacc[3][r]));
#pragma unroll
                for (int d = 1; d < 16; d <<= 1) mx = fmaxf(mx, __shfl_xor(mx, d, 64));
                float mnew = fmaxf(mrow[r], mx);
                float fs = __expf(mrow[r] - mnew);
                mrow[r] = mnew;
                float ps = 0.f;
#pragma unroll
                for (int nt = 0; nt < 4; ++nt) {
                    float pe = __expf(sacc[nt][r] - mnew);
                    sacc[nt][r] = pe;
                    ps += pe;
                }
#pragma unroll
                for (int d = 1; d < 16; d <<= 1) ps += __shfl_xor(ps, d, 64);
                lrow[r] = lrow[r] * fs + ps;
#pragma unroll
                for (int nt = 0; nt < 8; ++nt) oacc[nt][r] *= fs;
            }
            // P -> per-wave LDS (swizzled), read back as PV A-fragments (same-wave RAW)
#pragma unroll
            for (int nt = 0; nt < 4; ++nt)
#pragma unroll
                for (int r = 0; r < 4; ++r) {
                    int qrow = l4 * 4 + r;
                    int k = nt * 16 + l15;
                    Pl[wave][qrow * 64 + ((((k >> 3) ^ (qrow & 7)) << 3) | (k & 7))] = f2b(sacc[nt][r]);
                }
            bf16x8 pf0 = *(const bf16x8*)&Pl[wave][l15 * 64 + ((l4 ^ (l15 & 7)) << 3)];
            bf16x8 pf1 = *(const bf16x8*)&Pl[wave][l15 * 64 + (((4 + l4) ^ (l15 & 7)) << 3)];
#pragma unroll
            for (int nt = 0; nt < 8; ++nt) {
                int d = nt * 16 + l15;           // d&7 == l15&7
                bf16x8 v0 = *(const bf16x8*)&Vb[cur][d * 64 + ((l4 ^ (l15 & 7)) << 3)];
                bf16x8 v1 = *(const bf16x8*)&Vb[cur][d * 64 + (((4 + l4) ^ (l15 & 7)) << 3)];
                oacc[nt] = __builtin_amdgcn_mfma_f32_16x16x32_bf16(pf0, v0, oacc[nt], 0, 0, 0);
                oacc[nt] = __builtin_amdgcn_mfma_f32_16x16x32_bf16(pf1, v1, oacc[nt], 0, 0, 0);
            }
        }
        // ---- late half of V stage: write regs to the next buffer ----
        if (stage_next) {
#pragma unroll
            for (int jj = 0; jj < 8; ++jj) {
                int d0 = wave * 8 + jj, d1 = (8 + wave) * 8 + jj;
                Vb[cur ^ 1][d0 * 64 + ((((lane >> 3) ^ jj) << 3) | (lane & 7))] = vn0[jj];
                Vb[cur ^ 1][d1 * 64 + ((((lane >> 3) ^ jj) << 3) | (lane & 7))] = vn1[jj];
            }
        }
        __syncthreads();   // drains vmcnt (K gloads) + lgkmcnt (V writes); next iter ready
    }
#pragma unroll
    for (int nt = 0; nt < 8; ++nt)
#pragma unroll
        for (int r = 0; r < 4; ++r) {
            int qg = myqb * 64 + wl * 16 + l4 * 4 + r;
            O[(size_t)(b * Sv + qg) * 2048 + h * 128 + nt * 16 + l15] = f2b(oacc[nt][r] / lrow[r]);
        }
}

extern "C" void kernel_launch(void* const* d_in, const int* in_sizes, int n_in,
                              void* d_out, int out_size, void* d_ws, size_t ws_size,
                              hipStream_t stream) {
    const float* x   = (const float*)d_in[0];
    const float* fc  = (const float*)d_in[1];
    const int*   mod = (const int*)d_in[2];
    const float* wq  = (const float*)d_in[3];
    const float* wk  = (const float*)d_in[4];
    const float* wv  = (const float*)d_in[5];
    const float* wo  = (const float*)d_in[6];
    float* out = (float*)d_out;
    char* ws = (char*)d_ws;
    // workspace layout (bytes): total 100,663,296
    u16* Wqkv_t = (u16*)(ws);               // 3072 x 4096 bf16 (25.2 MB)
    u16* Wo_t   = (u16*)(ws + 25165824);    // 2048 x 4096 bf16 (16.8 MB)
    u16* Xdup   = (u16*)(ws + 41943040);    // 4096 x 4096 bf16 (33.6 MB), reused for Adup
    u16* QKV    = (u16*)(ws + 75497472);    // 4096 x 3072 bf16 (25.2 MB)
    u16* Attn   = (u16*)(ws);               // 4096 x 2048 bf16, aliases dead Wqkv_t region

    // weights -> B^T (N x K=4096) bf16
    transpose_cast<<<dim3(32, 64), 256, 0, stream>>>(wq, Wqkv_t, 2048);
    transpose_cast<<<dim3(8, 64),  256, 0, stream>>>(wk, Wqkv_t + (size_t)2048 * 4096, 512);
    transpose_cast<<<dim3(8, 64),  256, 0, stream>>>(wv, Wqkv_t + (size_t)2560 * 4096, 512);
    transpose_cast<<<dim3(32, 64), 256, 0, stream>>>(wo, Wo_t, 2048);
    // masked duplicated activations (f32 x -> bf16 Xdup)
    build_dup<float><<<4096, 256, 0, stream>>>(x, mod, Xdup);
    // QKV = Xdup (4096x4096) @ Wqkv' (4096x3072), bf16 out
    gemm_bt<u16><<<dim3(24, 32), 256, 0, stream>>>(Xdup, Wqkv_t, QKV, 4096, 3072, 4096);
    // RoPE on Q,K (+ fold score scale into Q)
    rope_kernel<<<20480, 256, 0, stream>>>(QKV, fc);
    // causal GQA attention -> Attn bf16 (paired q-tiles: uniform per-block work)
    attn_fwd<<<dim3(16, 16, 2), 512, 0, stream>>>(QKV, Attn);
    // output projection -> f32 out
    build_dup<u16><<<4096, 256, 0, stream>>>(Attn, mod, Xdup);
    gemm_bt<float><<<dim3(16, 32), 256, 0, stream>>>(Xdup, Wo_t, out, 4096, 2048, 4096);
}

// Round 5
// 353.653 us; speedup vs baseline: 2.2999x; 1.3037x over previous
//
#include <hip/hip_runtime.h>
#include <stdint.h>

typedef unsigned short u16;
typedef __bf16  bf16x8 __attribute__((ext_vector_type(8), may_alias));
typedef u16     u16x8  __attribute__((ext_vector_type(8), may_alias));
typedef float   f32x4  __attribute__((ext_vector_type(4)));
typedef float   f32x4u __attribute__((ext_vector_type(4), may_alias));

#define Bv   2
#define Sv   2048
#define Dv   2048
#define Hv   16
#define KVHv 4
#define HDv  128
#define Tv   (Bv*Sv)      // 4096 tokens
#define QKVN 3072         // 2048 Q + 512 K + 512 V
#define MAXROWS 4224      // 33 tiles of 128 (worst-case padded segments)

__device__ __forceinline__ float b2f(u16 u) {
    union { float f; uint32_t i; } x; x.i = ((uint32_t)u) << 16; return x.f;
}
__device__ __forceinline__ u16 f2b(float f) {
    union { float f; uint32_t u; } x; x.f = f;
    uint32_t r = x.u + 0x7fff + ((x.u >> 16) & 1);
    return (u16)(r >> 16);
}
// global -> LDS direct (16B per lane; LDS dest wave-uniform base, HW adds lane*16)
__device__ __forceinline__ void gload_lds16(const void* g, void* l) {
    __builtin_amdgcn_global_load_lds((__attribute__((address_space(1))) void*)(uintptr_t)g,
                                     (__attribute__((address_space(3))) void*)(uintptr_t)l,
                                     16, 0, 0);
}

// ---------- stable modality compaction: fwd[t]=compact pos, inv[pos]=t (or -1 pad) ----------
__global__ __launch_bounds__(1024) void scan_mod(const int* __restrict__ mod, int* __restrict__ fwd,
                                                 int* __restrict__ inv, int* __restrict__ hdr) {
    __shared__ int cnt[1024];
    const int tid = threadIdx.x;
    int m[4]; int c = 0;
#pragma unroll
    for (int e = 0; e < 4; ++e) { m[e] = mod[tid * 4 + e]; c += (m[e] == 0); }
    cnt[tid] = c;
    __syncthreads();
    for (int off = 1; off < 1024; off <<= 1) {
        int v = (tid >= off) ? cnt[tid - off] : 0;
        __syncthreads();
        cnt[tid] += v;
        __syncthreads();
    }
    const int c0 = cnt[1023];
    const int c0pad = (c0 + 127) & ~127;
    const int c1 = Tv - c0;
    const int total = c0pad + ((c1 + 127) & ~127);
    // fill all inv slots with -1 first (also covers [total, MAXROWS))
    for (int p = tid; p < MAXROWS; p += 1024) inv[p] = -1;
    __syncthreads();
    const int ex0 = cnt[tid] - c;            // mod-0 tokens before this chunk
    int z = 0;
#pragma unroll
    for (int e = 0; e < 4; ++e) {
        int t = tid * 4 + e;
        int pos;
        if (m[e] == 0) { pos = ex0 + z; ++z; }
        else           { pos = c0pad + (t - (ex0 + z)); }   // ones before t = t - zerosBefore
        fwd[t] = pos;
        inv[pos] = t;
    }
    if (tid == 0) { hdr[0] = total >> 7; hdr[1] = c0pad; hdr[2] = total; }
}

// ---------- gather + cast: Xg[pos] = bf16(x[inv[pos]]) or 0 ----------
__global__ void gather_cast(const float* __restrict__ x, const int* __restrict__ inv,
                            u16* __restrict__ Xg) {
    int v = blockIdx.x * 256 + threadIdx.x;   // MAXROWS*256 threads, 8 elems each
    int pos = v >> 8, c8 = (v & 255) * 8;
    int t = inv[pos];
    u16x8 val = {0, 0, 0, 0, 0, 0, 0, 0};
    if (t >= 0) {
        f32x4u a = *(const f32x4u*)&x[(size_t)t * Dv + c8];
        f32x4u b = *(const f32x4u*)&x[(size_t)t * Dv + c8 + 4];
#pragma unroll
        for (int j = 0; j < 4; ++j) { val[j] = f2b(a[j]); val[4 + j] = f2b(b[j]); }
    }
    *(u16x8*)&Xg[(size_t)pos * Dv + c8] = val;
}

// ---------- transpose + cast f32->bf16, batched over modality (blockIdx.z) ----------
// in: (2048 x C) f32 slab per z; out: (C x 2048) bf16, row-stride 2048
__global__ void transpose_cast(const float* __restrict__ in, u16* __restrict__ out, int C,
                               size_t inZ, size_t outZ) {
    in  += (size_t)blockIdx.z * inZ;
    out += (size_t)blockIdx.z * outZ;
    __shared__ u16 tile[64][72];
    const int tr = blockIdx.y * 64, tc = blockIdx.x * 64;
    const int tid = threadIdx.x;
#pragma unroll
    for (int i = 0; i < 4; ++i) {
        int s = tid + 256 * i;            // 1024 float4 = 64 rows x 16
        int r = s >> 4, c4 = (s & 15) * 4;
        f32x4u v = *(const f32x4u*)&in[(size_t)(tr + r) * C + tc + c4];
#pragma unroll
        for (int j = 0; j < 4; ++j) tile[r][c4 + j] = f2b(v[j]);
    }
    __syncthreads();
#pragma unroll
    for (int i = 0; i < 2; ++i) {
        int s = tid + 256 * i;
        int r = s >> 3, c8 = (s & 7) * 8;
        u16x8 v;
#pragma unroll
        for (int j = 0; j < 8; ++j) v[j] = tile[c8 + j][r];
        *(u16x8*)&out[(size_t)(tc + r) * 2048 + tr + c8] = v;
    }
}

// ---------- segmented GEMM: C[inv[row]] = A(total x 2048) * Wt_seg(Nfull x 2048)^T ----------
// 2-phase double-buffered K staging; per-M-tile modality segment selects the weight slab.
template <typename OutT>
__global__ __launch_bounds__(256) void gemm_seg(const u16* __restrict__ A,
                                                const u16* __restrict__ Bt,
                                                OutT* __restrict__ C,
                                                const int* __restrict__ inv,
                                                const int* __restrict__ hdr,
                                                int Nfull, int ldC) {
    const int total = hdr[2], c0pad = hdr[1];
    const int bm = blockIdx.y * 128;
    if (bm >= total) return;
    const u16* B = Bt + (size_t)((bm >= c0pad) ? 1 : 0) * Nfull * 2048;
    const int bn = blockIdx.x * 128;
    const int tid = threadIdx.x;
    const int wave = tid >> 6, lane = tid & 63;
    const int l15 = lane & 15, l4 = lane >> 4;
    const int wr = (wave >> 1) * 64, wc = (wave & 1) * 64;
    __shared__ u16 lA[2][128 * 64];
    __shared__ u16 lB[2][128 * 64];
    f32x4 acc[4][4] = {};
    auto STAGE = [&](int kt, int buf) {
#pragma unroll
        for (int i = 0; i < 4; ++i) {
            int s_u = wave * 64 + 256 * i;
            int s = s_u + lane;
            int r = s >> 3, k8 = (s & 7) * 8;
            gload_lds16(A + (size_t)(bm + r) * 2048 + kt * 64 + k8, &lA[buf][(size_t)s_u * 8]);
            gload_lds16(B + (size_t)(bn + r) * 2048 + kt * 64 + k8, &lB[buf][(size_t)s_u * 8]);
        }
    };
    STAGE(0, 0);
    __syncthreads();
    for (int kt = 0; kt < 32; ++kt) {
        const int cur = kt & 1;
        if (kt < 31) STAGE(kt + 1, cur ^ 1);   // async into other buffer; hides under MFMA
#pragma unroll
        for (int kc = 0; kc < 2; ++kc) {
            bf16x8 af[4], bfr[4];
#pragma unroll
            for (int i = 0; i < 4; ++i)
                af[i] = *(const bf16x8*)&lA[cur][(wr + i * 16 + l15) * 64 + kc * 32 + l4 * 8];
#pragma unroll
            for (int j = 0; j < 4; ++j)
                bfr[j] = *(const bf16x8*)&lB[cur][(wc + j * 16 + l15) * 64 + kc * 32 + l4 * 8];
#pragma unroll
            for (int i = 0; i < 4; ++i)
#pragma unroll
                for (int j = 0; j < 4; ++j)
                    acc[i][j] = __builtin_amdgcn_mfma_f32_16x16x32_bf16(af[i], bfr[j], acc[i][j], 0, 0, 0);
        }
        __syncthreads();   // drains vmcnt: next buffer staged; current reads done before overwrite
    }
    int tok[4][4];
#pragma unroll
    for (int i = 0; i < 4; ++i)
#pragma unroll
        for (int r = 0; r < 4; ++r)
            tok[i][r] = inv[bm + wr + i * 16 + l4 * 4 + r];
#pragma unroll
    for (int i = 0; i < 4; ++i)
#pragma unroll
        for (int j = 0; j < 4; ++j) {
            int col = bn + wc + j * 16 + l15;
#pragma unroll
            for (int r = 0; r < 4; ++r)
                if (tok[i][r] >= 0) {
                    if constexpr (sizeof(OutT) == 2) C[(size_t)tok[i][r] * ldC + col] = f2b(acc[i][j][r]);
                    else                             C[(size_t)tok[i][r] * ldC + col] = acc[i][j][r];
                }
        }
}

// ---------- RoPE in place on Q,K halves of QKV (bf16); freq_cis f32; folds 1/sqrt(HD) into Q ----------
__global__ void rope_kernel(u16* __restrict__ QKV, const float* __restrict__ fc) {
    int p = blockIdx.x * 256 + threadIdx.x;  // Tv*1280 total pairs
    const int t = p / 1280;
    const int r = p - t * 1280;
    const int s = t & (Sv - 1);
    int col, d2; float scale;
    if (r < 1024) { col = 2 * r;                d2 = r & 63;  scale = 0.08838834764831845f; }
    else          { int rr = r - 1024; col = 2048 + 2 * rr; d2 = rr & 63; scale = 1.0f; }
    u16* ptr = QKV + (size_t)t * QKVN + col;
    float t0 = b2f(ptr[0]), t1 = b2f(ptr[1]);
    f32x4u f = *(const f32x4u*)&fc[((size_t)s * 64 + d2) * 4];   // [c, -s, s, c]
    ptr[0] = f2b((t0 * f[0] + t1 * f[1]) * scale);
    ptr[1] = f2b((t0 * f[2] + t1 * f[3]) * scale);
}

// ---------- causal GQA flash attention (paired q-tiles, 2-phase K/V pipeline) ----------
// Output written COMPACT: row fwd[token], ready as the out-proj GEMM A-operand.
__global__ __launch_bounds__(512) void attn_fwd(const u16* __restrict__ QKV, u16* __restrict__ Ag,
                                                const int* __restrict__ fwd) {
    const int p = blockIdx.x;                 // pair id 0..15
    const int h = blockIdx.y, b = blockIdx.z;
    const int kvh = h >> 2;
    const int tid = threadIdx.x, wave = tid >> 6, lane = tid & 63;
    const int wgrp = wave >> 2, wl = wave & 3;
    const int l15 = lane & 15, l4 = lane >> 4;
    const int myqb = wgrp ? (31 - p) : p;     // this wave-group's q-tile
    __shared__ u16 Kb[2][64 * 128];
    __shared__ u16 Vb[2][128 * 64];
    __shared__ u16 Pl[8][16 * 64];

    bf16x8 qf[4];
    {
        const size_t qrow = (size_t)(b * Sv + myqb * 64 + wl * 16 + l15);
#pragma unroll
        for (int kc = 0; kc < 4; ++kc)
            qf[kc] = *(const bf16x8*)&QKV[qrow * QKVN + h * 128 + kc * 32 + l4 * 8];
    }
    f32x4 oacc[8] = {};
    float mrow[4] = {-1e30f, -1e30f, -1e30f, -1e30f};
    float lrow[4] = {0.f, 0.f, 0.f, 0.f};

    const size_t kvbase = (size_t)b * Sv * QKVN + 2048 + kvh * 128;

    // ---- prologue: stage tile 0 into buffer 0 ----
    {
#pragma unroll
        for (int i = 0; i < 2; ++i) {
            int s_u = wave * 64 + 512 * i;
            int s = s_u + lane;
            int r = s >> 4;
            int cs = (s & 15) ^ (r & 7);
            gload_lds16(QKV + kvbase + (size_t)r * QKVN + cs * 8, &Kb[0][(size_t)s_u * 8]);
        }
        u16x8 vr0, vr1;
        vr0 = *(const u16x8*)&QKV[kvbase + 512 + (size_t)lane * QKVN + (0 * 8 + wave) * 8];
        vr1 = *(const u16x8*)&QKV[kvbase + 512 + (size_t)lane * QKVN + (1 * 8 + wave) * 8];
#pragma unroll
        for (int jj = 0; jj < 8; ++jj) {
            int d0 = wave * 8 + jj, d1 = (8 + wave) * 8 + jj;
            Vb[0][d0 * 64 + ((((lane >> 3) ^ jj) << 3) | (lane & 7))] = vr0[jj];
            Vb[0][d1 * 64 + ((((lane >> 3) ^ jj) << 3) | (lane & 7))] = vr1[jj];
        }
    }
    __syncthreads();

    for (int j = 0; j < 32; ++j) {
        const int cur = j & 1;
        const bool stage_next = (j < 31);
        u16x8 vn0, vn1;
        if (stage_next) {
            const size_t nb = kvbase + (size_t)(j + 1) * 64 * QKVN;
#pragma unroll
            for (int i = 0; i < 2; ++i) {
                int s_u = wave * 64 + 512 * i;
                int s = s_u + lane;
                int r = s >> 4;
                int cs = (s & 15) ^ (r & 7);
                gload_lds16(QKV + nb + (size_t)r * QKVN + cs * 8, &Kb[cur ^ 1][(size_t)s_u * 8]);
            }
            vn0 = *(const u16x8*)&QKV[nb + 512 + (size_t)lane * QKVN + (0 * 8 + wave) * 8];
            vn1 = *(const u16x8*)&QKV[nb + 512 + (size_t)lane * QKVN + (1 * 8 + wave) * 8];
        }
        if (j <= myqb) {
            f32x4 sacc[4] = {};
#pragma unroll
            for (int kc = 0; kc < 4; ++kc)
#pragma unroll
                for (int nt = 0; nt < 4; ++nt) {
                    int cs = ((kc * 4 + l4) ^ (l15 & 7));
                    bf16x8 kf = *(const bf16x8*)&Kb[cur][(nt * 16 + l15) * 128 + cs * 8];
                    sacc[nt] = __builtin_amdgcn_mfma_f32_16x16x32_bf16(qf[kc], kf, sacc[nt], 0, 0, 0);
                }
            if (j == myqb) {
#pragma unroll
                for (int nt = 0; nt < 4; ++nt)
#pragma unroll
                    for (int r = 0; r < 4; ++r)
                        if (nt * 16 + l15 > wl * 16 + l4 * 4 + r)
                            sacc[nt][r] = -1e30f;
            }
#pragma unroll
            for (int r = 0; r < 4; ++r) {
                float mx = fmaxf(fmaxf(sacc[0][r], sacc[1][r]), fmaxf(sacc[2][r], sacc[3][r]));
#pragma unroll
                for (int d = 1; d < 16; d <<= 1) mx = fmaxf(mx, __shfl_xor(mx, d, 64));
                float mnew = fmaxf(mrow[r], mx);
                float fs = __expf(mrow[r] - mnew);
                mrow[r] = mnew;
                float ps = 0.f;
#pragma unroll
                for (int nt = 0; nt < 4; ++nt) {
                    float pe = __expf(sacc[nt][r] - mnew);
                    sacc[nt][r] = pe;
                    ps += pe;
                }
#pragma unroll
                for (int d = 1; d < 16; d <<= 1) ps += __shfl_xor(ps, d, 64);
                lrow[r] = lrow[r] * fs + ps;
#pragma unroll
                for (int nt = 0; nt < 8; ++nt) oacc[nt][r] *= fs;
            }
#pragma unroll
            for (int nt = 0; nt < 4; ++nt)
#pragma unroll
                for (int r = 0; r < 4; ++r) {
                    int qrow = l4 * 4 + r;
                    int k = nt * 16 + l15;
                    Pl[wave][qrow * 64 + ((((k >> 3) ^ (qrow & 7)) << 3) | (k & 7))] = f2b(sacc[nt][r]);
                }
            bf16x8 pf0 = *(const bf16x8*)&Pl[wave][l15 * 64 + ((l4 ^ (l15 & 7)) << 3)];
            bf16x8 pf1 = *(const bf16x8*)&Pl[wave][l15 * 64 + (((4 + l4) ^ (l15 & 7)) << 3)];
#pragma unroll
            for (int nt = 0; nt < 8; ++nt) {
                int d = nt * 16 + l15;           // d&7 == l15&7
                bf16x8 v0 = *(const bf16x8*)&Vb[cur][d * 64 + ((l4 ^ (l15 & 7)) << 3)];
                bf16x8 v1 = *(const bf16x8*)&Vb[cur][d * 64 + (((4 + l4) ^ (l15 & 7)) << 3)];
                oacc[nt] = __builtin_amdgcn_mfma_f32_16x16x32_bf16(pf0, v0, oacc[nt], 0, 0, 0);
                oacc[nt] = __builtin_amdgcn_mfma_f32_16x16x32_bf16(pf1, v1, oacc[nt], 0, 0, 0);
            }
        }
        if (stage_next) {
#pragma unroll
            for (int jj = 0; jj < 8; ++jj) {
                int d0 = wave * 8 + jj, d1 = (8 + wave) * 8 + jj;
                Vb[cur ^ 1][d0 * 64 + ((((lane >> 3) ^ jj) << 3) | (lane & 7))] = vn0[jj];
                Vb[cur ^ 1][d1 * 64 + ((((lane >> 3) ^ jj) << 3) | (lane & 7))] = vn1[jj];
            }
        }
        __syncthreads();
    }
    int rowmap[4];
#pragma unroll
    for (int r = 0; r < 4; ++r)
        rowmap[r] = fwd[b * Sv + myqb * 64 + wl * 16 + l4 * 4 + r];
#pragma unroll
    for (int nt = 0; nt < 8; ++nt)
#pragma unroll
        for (int r = 0; r < 4; ++r)
            Ag[(size_t)rowmap[r] * 2048 + h * 128 + nt * 16 + l15] = f2b(oacc[nt][r] / lrow[r]);
}

extern "C" void kernel_launch(void* const* d_in, const int* in_sizes, int n_in,
                              void* d_out, int out_size, void* d_ws, size_t ws_size,
                              hipStream_t stream) {
    const float* x   = (const float*)d_in[0];
    const float* fc  = (const float*)d_in[1];
    const int*   mod = (const int*)d_in[2];
    const float* wq  = (const float*)d_in[3];
    const float* wk  = (const float*)d_in[4];
    const float* wv  = (const float*)d_in[5];
    const float* wo  = (const float*)d_in[6];
    float* out = (float*)d_out;
    char* ws = (char*)d_ws;
    // workspace layout (bytes), total ~84.5 MB:
    u16* Wqkv_t = (u16*)(ws);               // 2 x (3072 x 2048) bf16 = 25,165,824
    u16* Wo_t   = (u16*)(ws + 25165824);    // 2 x (2048 x 2048) bf16 = 16,777,216
    u16* Xg     = (u16*)(ws + 41943040);    // MAXROWS x 2048 bf16 = 17,301,504 (reused as Ag)
    u16* QKV    = (u16*)(ws + 59244544);    // 4096 x 3072 bf16 = 25,165,824
    int* fwd    = (int*)(ws + 84410368);    // 4096 ints
    int* inv    = (int*)(ws + 84426752);    // MAXROWS ints (+pad)
    int* hdr    = (int*)(ws + 84444160);    // small header
    u16* Ag     = Xg;                        // Xg dead after QKV GEMM

    // per-modality weights -> B^T (N x K=2048) bf16
    transpose_cast<<<dim3(32, 32, 2), 256, 0, stream>>>(wq, Wqkv_t, 2048,
        (size_t)2048 * 2048, (size_t)3072 * 2048);
    transpose_cast<<<dim3(8, 32, 2),  256, 0, stream>>>(wk, Wqkv_t + (size_t)2048 * 2048, 512,
        (size_t)2048 * 512,  (size_t)3072 * 2048);
    transpose_cast<<<dim3(8, 32, 2),  256, 0, stream>>>(wv, Wqkv_t + (size_t)2560 * 2048, 512,
        (size_t)2048 * 512,  (size_t)3072 * 2048);
    transpose_cast<<<dim3(32, 32, 2), 256, 0, stream>>>(wo, Wo_t, 2048,
        (size_t)2048 * 2048, (size_t)2048 * 2048);
    // modality compaction
    scan_mod<<<1, 1024, 0, stream>>>(mod, fwd, inv, hdr);
    gather_cast<<<MAXROWS, 256, 0, stream>>>(x, inv, Xg);
    // QKV = Xg @ Wqkv_m^T (K=2048), scattered token-major
    gemm_seg<u16><<<dim3(24, 33), 256, 0, stream>>>(Xg, Wqkv_t, QKV, inv, hdr, 3072, 3072);
    // RoPE on Q,K (+ fold score scale into Q)
    rope_kernel<<<20480, 256, 0, stream>>>(QKV, fc);
    // causal GQA attention -> compact Ag rows via fwd
    attn_fwd<<<dim3(16, 16, 2), 512, 0, stream>>>(QKV, Ag, fwd);
    // out = Ag @ Wo_m^T, scattered token-major f32
    gemm_seg<float><<<dim3(16, 33), 256, 0, stream>>>(Ag, Wo_t, out, inv, hdr, 2048, 2048);
}